// Round 1
// baseline (4716.360 us; speedup 1.0000x reference)
//
#include <hip/hip_runtime.h>
#include <cmath>

// ---------------------------------------------------------------------------
// Tiled fp32 NT-GEMM: C[m][n] = sum_k A[m*lda+k] * B[n*ldb+k]
// 64x64 tile, 256 threads, 4x4 per-thread microtile, K-step 16.
// EPI 0: plain store (with n<N guard)
// EPI 1: split store: n<2048 -> C (x half), else -> C2 (z half)
// EPI 2: v += bias[n]; softplus; store
// ---------------------------------------------------------------------------
template<int EPI>
__global__ __launch_bounds__(256) void gemm_nt(
    const float* __restrict__ A, const float* __restrict__ B,
    float* __restrict__ C, float* __restrict__ C2,
    const float* __restrict__ bias,
    int N, int K, int lda, int ldb, int ldc)
{
    __shared__ float As[16][68];   // [k][m], pad to 68 to keep 16B align, break pow2
    __shared__ float Bs[16][68];   // [k][n]

    const int tid = threadIdx.x;
    const int tx = tid & 15;       // n-group
    const int ty = tid >> 4;       // m-group
    const int bm = blockIdx.x * 64;
    const int bn = blockIdx.y * 64;

    const int r  = tid >> 2;           // 0..63 row within tile
    const int kc = (tid & 3) << 2;     // 0,4,8,12

    float acc[4][4];
#pragma unroll
    for (int i = 0; i < 4; ++i)
#pragma unroll
        for (int j = 0; j < 4; ++j) acc[i][j] = 0.f;

    for (int k0 = 0; k0 < K; k0 += 16) {
        float4 av = *(const float4*)(A + (size_t)(bm + r) * lda + k0 + kc);
        const int cB = bn + r;
        float4 bv = make_float4(0.f, 0.f, 0.f, 0.f);
        if (cB < N) bv = *(const float4*)(B + (size_t)cB * ldb + k0 + kc);

        As[kc + 0][r] = av.x; As[kc + 1][r] = av.y;
        As[kc + 2][r] = av.z; As[kc + 3][r] = av.w;
        Bs[kc + 0][r] = bv.x; Bs[kc + 1][r] = bv.y;
        Bs[kc + 2][r] = bv.z; Bs[kc + 3][r] = bv.w;
        __syncthreads();

#pragma unroll
        for (int kk = 0; kk < 16; ++kk) {
            float4 a4 = *(const float4*)&As[kk][ty << 2];
            float4 b4 = *(const float4*)&Bs[kk][tx << 2];
            float a[4] = {a4.x, a4.y, a4.z, a4.w};
            float b[4] = {b4.x, b4.y, b4.z, b4.w};
#pragma unroll
            for (int i = 0; i < 4; ++i)
#pragma unroll
                for (int j = 0; j < 4; ++j)
                    acc[i][j] = fmaf(a[i], b[j], acc[i][j]);
        }
        __syncthreads();
    }

#pragma unroll
    for (int i = 0; i < 4; ++i) {
        const int m = bm + (ty << 2) + i;
#pragma unroll
        for (int j = 0; j < 4; ++j) {
            const int n = bn + (tx << 2) + j;
            float v = acc[i][j];
            if (EPI == 0) {
                if (n < N) C[(size_t)m * ldc + n] = v;
            } else if (EPI == 1) {
                if (n < 2048) C[(size_t)m * 2048 + n] = v;
                else          C2[(size_t)m * 2048 + (n - 2048)] = v;
            } else {
                v += bias[n];
                v = (v > 20.f) ? v : log1pf(expf(v));
                C[(size_t)m * ldc + n] = v;
            }
        }
    }
}

// ---------------------------------------------------------------------------
// Depthwise causal conv (width 4, left pad 3) + bias + SiLU.
// Layout (B, L, D) row-major; one thread per output element.
// ---------------------------------------------------------------------------
__global__ __launch_bounds__(256) void conv_silu(
    const float* __restrict__ xin, const float* __restrict__ w,
    const float* __restrict__ bias, float* __restrict__ xout,
    int L, int D)
{
    const long long idx = (long long)blockIdx.x * 256 + threadIdx.x;
    const int d = (int)(idx % D);
    const long long bl = idx / D;
    const int l = (int)(bl % L);

    const float w0 = w[d * 4 + 0], w1 = w[d * 4 + 1];
    const float w2 = w[d * 4 + 2], w3 = w[d * 4 + 3];

    float acc = bias[d];
    acc = fmaf(w3, xin[idx], acc);
    if (l >= 1) acc = fmaf(w2, xin[idx - D], acc);
    if (l >= 2) acc = fmaf(w1, xin[idx - 2LL * D], acc);
    if (l >= 3) acc = fmaf(w0, xin[idx - 3LL * D], acc);

    // SiLU
    const float s = acc / (1.f + __expf(-acc));
    xout[idx] = s;
}

// ---------------------------------------------------------------------------
// Selective scan. One lane per (b, d, n) state; 16 lanes = one channel.
// Gate (y *= silu(z)) fused into the store. y written in-place over xconv.
// ---------------------------------------------------------------------------
__global__ __launch_bounds__(256) void scan_kernel(
    const float* __restrict__ xconv,  // (B,L,D)  input x (post conv+silu)
    const float* __restrict__ dt,     // (B,L,D)  softplus'd
    const float* __restrict__ xdbl,   // (B*L,96) cols 64..79 = B, 80..95 = C
    const float* __restrict__ A_log,  // (D,16)
    const float* __restrict__ Dp,     // (D,)
    const float* __restrict__ z,      // (B,L,D)
    float* __restrict__ y)            // (B,L,D)  (== xconv, in-place)
{
    const int tid = blockIdx.x * 256 + threadIdx.x;   // 0..65535
    const int g = tid >> 4;        // channel group 0..4095
    const int n = tid & 15;        // state index
    const int b = g >> 11;         // /2048
    const int d = g & 2047;

    const float a  = -__expf(A_log[d * 16 + n]);
    const float Dv = Dp[d];

    float h = 0.f;
    const long long rowBase = (long long)b * 4096;

    for (int l = 0; l < 4096; ++l) {
        const long long row = rowBase + l;
        const float dtv = dt[row * 2048 + d];
        const float xv  = xconv[row * 2048 + d];
        const float Bv  = xdbl[row * 96 + 64 + n];
        const float Cv  = xdbl[row * 96 + 80 + n];

        const float dA = __expf(dtv * a);
        h = fmaf(h, dA, dtv * xv * Bv);

        float contrib = h * Cv;
        contrib += __shfl_xor(contrib, 1);
        contrib += __shfl_xor(contrib, 2);
        contrib += __shfl_xor(contrib, 4);
        contrib += __shfl_xor(contrib, 8);

        if (n == 0) {
            const float zv = z[row * 2048 + d];
            float yv = contrib + xv * Dv;
            yv = yv * (zv / (1.f + __expf(-zv)));
            y[row * 2048 + d] = yv;
        }
    }
}

// ---------------------------------------------------------------------------
extern "C" void kernel_launch(void* const* d_in, const int* in_sizes, int n_in,
                              void* d_out, int out_size, void* d_ws, size_t ws_size,
                              hipStream_t stream)
{
    const float* hidden     = (const float*)d_in[0];
    const float* in_proj_w  = (const float*)d_in[1];
    const float* conv_w     = (const float*)d_in[2];
    const float* conv_b     = (const float*)d_in[3];
    const float* x_proj_w   = (const float*)d_in[4];
    const float* dt_proj_w  = (const float*)d_in[5];
    const float* dt_proj_b  = (const float*)d_in[6];
    const float* A_log      = (const float*)d_in[7];
    const float* Dvec       = (const float*)d_in[8];
    const float* out_proj_w = (const float*)d_in[9];
    float* out = (float*)d_out;

    const int L = 4096, dinner = 2048;
    const int M = 2 * L;  // 8192 rows (B*L)

    // workspace layout (floats)
    float* z     = (float*)d_ws;                     // M*2048
    float* xraw  = z     + (size_t)M * dinner;       // M*2048 (reused as dt)
    float* xconv = xraw  + (size_t)M * dinner;       // M*2048 (reused as y)
    float* xdbl  = xconv + (size_t)M * dinner;       // M*96

    // 1. in_proj: (M x 1024) x (4096 x 1024)^T -> split x | z
    gemm_nt<1><<<dim3(M / 64, 4096 / 64), 256, 0, stream>>>(
        hidden, in_proj_w, xraw, z, nullptr, 4096, 1024, 1024, 1024, 0);

    // 2. depthwise conv + bias + SiLU
    conv_silu<<<(M * (long long)dinner) / 256, 256, 0, stream>>>(
        xraw, conv_w, conv_b, xconv, L, dinner);

    // 3. x_proj: (M x 2048) x (96 x 2048)^T -> xdbl (M x 96)
    gemm_nt<0><<<dim3(M / 64, 2), 256, 0, stream>>>(
        xconv, x_proj_w, xdbl, nullptr, nullptr, 96, 2048, 2048, 2048, 96);

    // 4. dt_proj: (M x 64 from xdbl, lda 96) x (2048 x 64)^T -> dt (=xraw), softplus+bias
    gemm_nt<2><<<dim3(M / 64, 2048 / 64), 256, 0, stream>>>(
        xdbl, dt_proj_w, xraw, nullptr, dt_proj_b, 2048, 64, 96, 64, 2048);

    // 5. selective scan + gate (y in-place over xconv)
    scan_kernel<<<256, 256, 0, stream>>>(
        xconv, xraw, xdbl, A_log, Dvec, z, xconv);

    // 6. out_proj: (M x 2048) x (1024 x 2048)^T -> out
    gemm_nt<0><<<dim3(M / 64, 1024 / 64), 256, 0, stream>>>(
        xconv, out_proj_w, out, nullptr, nullptr, 1024, 2048, 2048, 2048, 1024);
}

// Round 2
// 2222.195 us; speedup vs baseline: 2.1224x; 2.1224x over previous
//
#include <hip/hip_runtime.h>
#include <cmath>

#define CH 128          // chunk length
#define NC 32           // 4096 / CH

// ---------------------------------------------------------------------------
// Tiled fp32 NT-GEMM: C[m][n] = sum_k A[m*lda+k] * B[n*ldb+k]
// 64x64 tile, 256 threads, 4x4 per-thread microtile, K-step 16.
// EPI 0: plain store (with n<N guard)
// EPI 1: split store: n<2048 -> C (x half), else -> C2 (z half)
// EPI 2: v += bias[n]; softplus; store
// ---------------------------------------------------------------------------
template<int EPI>
__global__ __launch_bounds__(256) void gemm_nt(
    const float* __restrict__ A, const float* __restrict__ B,
    float* __restrict__ C, float* __restrict__ C2,
    const float* __restrict__ bias,
    int N, int K, int lda, int ldb, int ldc)
{
    __shared__ float As[16][68];
    __shared__ float Bs[16][68];

    const int tid = threadIdx.x;
    const int tx = tid & 15;
    const int ty = tid >> 4;
    const int bm = blockIdx.x * 64;
    const int bn = blockIdx.y * 64;

    const int r  = tid >> 2;
    const int kc = (tid & 3) << 2;

    float acc[4][4];
#pragma unroll
    for (int i = 0; i < 4; ++i)
#pragma unroll
        for (int j = 0; j < 4; ++j) acc[i][j] = 0.f;

    for (int k0 = 0; k0 < K; k0 += 16) {
        float4 av = *(const float4*)(A + (size_t)(bm + r) * lda + k0 + kc);
        const int cB = bn + r;
        float4 bv = make_float4(0.f, 0.f, 0.f, 0.f);
        if (cB < N) bv = *(const float4*)(B + (size_t)cB * ldb + k0 + kc);

        As[kc + 0][r] = av.x; As[kc + 1][r] = av.y;
        As[kc + 2][r] = av.z; As[kc + 3][r] = av.w;
        Bs[kc + 0][r] = bv.x; Bs[kc + 1][r] = bv.y;
        Bs[kc + 2][r] = bv.z; Bs[kc + 3][r] = bv.w;
        __syncthreads();

#pragma unroll
        for (int kk = 0; kk < 16; ++kk) {
            float4 a4 = *(const float4*)&As[kk][ty << 2];
            float4 b4 = *(const float4*)&Bs[kk][tx << 2];
            float a[4] = {a4.x, a4.y, a4.z, a4.w};
            float b[4] = {b4.x, b4.y, b4.z, b4.w};
#pragma unroll
            for (int i = 0; i < 4; ++i)
#pragma unroll
                for (int j = 0; j < 4; ++j)
                    acc[i][j] = fmaf(a[i], b[j], acc[i][j]);
        }
        __syncthreads();
    }

#pragma unroll
    for (int i = 0; i < 4; ++i) {
        const int m = bm + (ty << 2) + i;
#pragma unroll
        for (int j = 0; j < 4; ++j) {
            const int n = bn + (tx << 2) + j;
            float v = acc[i][j];
            if (EPI == 0) {
                if (n < N) C[(size_t)m * ldc + n] = v;
            } else if (EPI == 1) {
                if (n < 2048) C[(size_t)m * 2048 + n] = v;
                else          C2[(size_t)m * 2048 + (n - 2048)] = v;
            } else {
                v += bias[n];
                v = (v > 20.f) ? v : log1pf(expf(v));
                C[(size_t)m * ldc + n] = v;
            }
        }
    }
}

// ---------------------------------------------------------------------------
// Depthwise causal conv (width 4, left pad 3) + bias + SiLU.
// ---------------------------------------------------------------------------
__global__ __launch_bounds__(256) void conv_silu(
    const float* __restrict__ xin, const float* __restrict__ w,
    const float* __restrict__ bias, float* __restrict__ xout,
    int L, int D)
{
    const long long idx = (long long)blockIdx.x * 256 + threadIdx.x;
    const int d = (int)(idx % D);
    const long long bl = idx / D;
    const int l = (int)(bl % L);

    const float w0 = w[d * 4 + 0], w1 = w[d * 4 + 1];
    const float w2 = w[d * 4 + 2], w3 = w[d * 4 + 3];

    float acc = bias[d];
    acc = fmaf(w3, xin[idx], acc);
    if (l >= 1) acc = fmaf(w2, xin[idx - D], acc);
    if (l >= 2) acc = fmaf(w1, xin[idx - 2LL * D], acc);
    if (l >= 3) acc = fmaf(w0, xin[idx - 3LL * D], acc);

    const float s = acc / (1.f + __expf(-acc));
    xout[idx] = s;
}

// ---------------------------------------------------------------------------
// Chunked selective scan, pass 1: per-chunk local scan.
// Block = 256 threads = 16 channels x 16 states. One block per (dgrp, c, b).
// Outputs (layout [b][c][d][n]): Sbuf = local final state (h0=0),
//                                Pbuf = chunk decay exp(a * sum dt).
// ---------------------------------------------------------------------------
__global__ __launch_bounds__(256) void scan_chunk_local(
    const float* __restrict__ xconv, const float* __restrict__ dt,
    const float* __restrict__ xdbl,  const float* __restrict__ A_log,
    float* __restrict__ Sbuf, float* __restrict__ Pbuf)
{
    const int n      = threadIdx.x & 15;
    const int dlocal = threadIdx.x >> 4;
    const int d = blockIdx.x * 16 + dlocal;
    const int c = blockIdx.y;
    const int b = blockIdx.z;

    const float a = -__expf(A_log[d * 16 + n]);

    float S = 0.f, sumdt = 0.f;
    const long long rowBase = (long long)b * 4096 + (long long)c * CH;

#pragma unroll 4
    for (int i = 0; i < CH; ++i) {
        const long long row = rowBase + i;
        const float dtv = dt[row * 2048 + d];
        const float xv  = xconv[row * 2048 + d];
        const float Bv  = xdbl[row * 96 + 64 + n];
        const float dA  = __expf(dtv * a);
        S = fmaf(S, dA, dtv * xv * Bv);
        sumdt += dtv;
    }
    const float P = __expf(sumdt * a);
    const size_t idx = ((((size_t)b * NC + c) * 2048) + d) * 16 + n;
    Sbuf[idx] = S;
    Pbuf[idx] = P;
}

// ---------------------------------------------------------------------------
// Pass 2: sequential prefix over chunks per (b,d,n). In-place: Sbuf becomes
// the chunk-ENTERING state H_c.
// ---------------------------------------------------------------------------
__global__ __launch_bounds__(256) void scan_chunk_prefix(
    float* __restrict__ Sbuf, const float* __restrict__ Pbuf)
{
    const int tid = blockIdx.x * 256 + threadIdx.x;  // 0..65535 = b*32768 + d*16 + n
    const int b  = tid >> 15;
    const int dn = tid & 32767;

    float H = 0.f;
    for (int c = 0; c < NC; ++c) {
        const size_t idx = ((size_t)b * NC + c) * 32768 + dn;
        const float S = Sbuf[idx];
        const float P = Pbuf[idx];
        Sbuf[idx] = H;
        H = fmaf(P, H, S);
    }
}

// ---------------------------------------------------------------------------
// Pass 3: recompute local scan seeded with H_c, reduce over n, gate, store y.
// y written in-place over xconv (reads of (row,d) precede the write in the
// same wave-synchronous iteration; no other block touches this chunk).
// ---------------------------------------------------------------------------
__global__ __launch_bounds__(256) void scan_chunk_final(
    const float* __restrict__ xconv, const float* __restrict__ dt,
    const float* __restrict__ xdbl,  const float* __restrict__ A_log,
    const float* __restrict__ Dp,    const float* __restrict__ z,
    const float* __restrict__ Hbuf,  float* __restrict__ y)
{
    const int n      = threadIdx.x & 15;
    const int dlocal = threadIdx.x >> 4;
    const int d = blockIdx.x * 16 + dlocal;
    const int c = blockIdx.y;
    const int b = blockIdx.z;

    const float a  = -__expf(A_log[d * 16 + n]);
    const float Dv = Dp[d];

    float h = Hbuf[((((size_t)b * NC + c) * 2048) + d) * 16 + n];
    const long long rowBase = (long long)b * 4096 + (long long)c * CH;

    for (int i = 0; i < CH; ++i) {
        const long long row = rowBase + i;
        const float dtv = dt[row * 2048 + d];
        const float xv  = xconv[row * 2048 + d];
        const float Bv  = xdbl[row * 96 + 64 + n];
        const float Cv  = xdbl[row * 96 + 80 + n];
        const float dA  = __expf(dtv * a);
        h = fmaf(h, dA, dtv * xv * Bv);

        float contrib = h * Cv;
        contrib += __shfl_xor(contrib, 1);
        contrib += __shfl_xor(contrib, 2);
        contrib += __shfl_xor(contrib, 4);
        contrib += __shfl_xor(contrib, 8);

        if (n == 0) {
            const float zv = z[row * 2048 + d];
            float yv = contrib + xv * Dv;
            yv = yv * (zv / (1.f + __expf(-zv)));
            y[row * 2048 + d] = yv;
        }
    }
}

// ---------------------------------------------------------------------------
extern "C" void kernel_launch(void* const* d_in, const int* in_sizes, int n_in,
                              void* d_out, int out_size, void* d_ws, size_t ws_size,
                              hipStream_t stream)
{
    const float* hidden     = (const float*)d_in[0];
    const float* in_proj_w  = (const float*)d_in[1];
    const float* conv_w     = (const float*)d_in[2];
    const float* conv_b     = (const float*)d_in[3];
    const float* x_proj_w   = (const float*)d_in[4];
    const float* dt_proj_w  = (const float*)d_in[5];
    const float* dt_proj_b  = (const float*)d_in[6];
    const float* A_log      = (const float*)d_in[7];
    const float* Dvec       = (const float*)d_in[8];
    const float* out_proj_w = (const float*)d_in[9];
    float* out = (float*)d_out;

    const int L = 4096, dinner = 2048;
    const int M = 2 * L;  // 8192 rows (B*L)

    // workspace layout (floats)
    float* z     = (float*)d_ws;                     // M*2048
    float* xraw  = z     + (size_t)M * dinner;       // M*2048 (reused as dt)
    float* xconv = xraw  + (size_t)M * dinner;       // M*2048 (reused as y)
    float* xdbl  = xconv + (size_t)M * dinner;       // M*96
    float* Sbuf  = xdbl  + (size_t)M * 96;           // B*NC*D*16 = 2.1M floats
    float* Pbuf  = Sbuf  + (size_t)2 * NC * dinner * 16;

    // 1. in_proj: (M x 1024) x (4096 x 1024)^T -> split x | z
    gemm_nt<1><<<dim3(M / 64, 4096 / 64), 256, 0, stream>>>(
        hidden, in_proj_w, xraw, z, nullptr, 4096, 1024, 1024, 1024, 0);

    // 2. depthwise conv + bias + SiLU
    conv_silu<<<(M * (long long)dinner) / 256, 256, 0, stream>>>(
        xraw, conv_w, conv_b, xconv, L, dinner);

    // 3. x_proj: (M x 2048) x (96 x 2048)^T -> xdbl (M x 96)
    gemm_nt<0><<<dim3(M / 64, 2), 256, 0, stream>>>(
        xconv, x_proj_w, xdbl, nullptr, nullptr, 96, 2048, 2048, 2048, 96);

    // 4. dt_proj: (M x 64 from xdbl, lda 96) x (2048 x 64)^T -> dt (=xraw)
    gemm_nt<2><<<dim3(M / 64, 2048 / 64), 256, 0, stream>>>(
        xdbl, dt_proj_w, xraw, nullptr, dt_proj_b, 2048, 64, 96, 64, 2048);

    // 5. chunked selective scan
    scan_chunk_local<<<dim3(dinner / 16, NC, 2), 256, 0, stream>>>(
        xconv, xraw, xdbl, A_log, Sbuf, Pbuf);
    scan_chunk_prefix<<<256, 256, 0, stream>>>(Sbuf, Pbuf);
    scan_chunk_final<<<dim3(dinner / 16, NC, 2), 256, 0, stream>>>(
        xconv, xraw, xdbl, A_log, Dvec, z, Sbuf, xconv);

    // 6. out_proj: (M x 2048) x (1024 x 2048)^T -> out
    gemm_nt<0><<<dim3(M / 64, 1024 / 64), 256, 0, stream>>>(
        xconv, out_proj_w, out, nullptr, nullptr, 1024, 2048, 2048, 2048, 1024);
}

// Round 4
// 1110.304 us; speedup vs baseline: 4.2478x; 2.0014x over previous
//
#include <hip/hip_runtime.h>
#include <cmath>

#define CH 128          // scan chunk length
#define NC 32           // 4096 / CH

typedef __bf16 bf16_t;
typedef __attribute__((ext_vector_type(8))) __bf16 bf16x8;
typedef __attribute__((ext_vector_type(4))) __bf16 bf16x4;
typedef __attribute__((ext_vector_type(4))) float f32x4;

// CK idiom: generic->AS1/AS3 via uintptr for global_load_lds (width 16).
#define GLOAD_LDS16(gp, lp)                                                     \
    __builtin_amdgcn_global_load_lds(                                           \
        (const __attribute__((address_space(1))) unsigned int*)(uintptr_t)(gp), \
        (__attribute__((address_space(3))) unsigned int*)(uintptr_t)(lp),       \
        16, 0, 0)

// ---------------------------------------------------------------------------
// fp32 -> (hi, lo) bf16 split.  4 floats per thread.
// ---------------------------------------------------------------------------
__global__ __launch_bounds__(256) void split_hl(
    const float* __restrict__ in, bf16_t* __restrict__ hi,
    bf16_t* __restrict__ lo, int n4)
{
    const int i = blockIdx.x * 256 + threadIdx.x;
    if (i >= n4) return;
    const float4 v = ((const float4*)in)[i];
    const bf16_t h0 = (bf16_t)v.x, h1 = (bf16_t)v.y,
                 h2 = (bf16_t)v.z, h3 = (bf16_t)v.w;
    bf16x4 hv = {h0, h1, h2, h3};
    bf16x4 lv = {(bf16_t)(v.x - (float)h0), (bf16_t)(v.y - (float)h1),
                 (bf16_t)(v.z - (float)h2), (bf16_t)(v.w - (float)h3)};
    ((bf16x4*)hi)[i] = hv;
    ((bf16x4*)lo)[i] = lv;
}

// ---------------------------------------------------------------------------
// Split-precision MFMA NT-GEMM:  C = A.B^T computed as Ah.Bh + Al.Bh + Ah.Bl
// A [M][K] fp32 (reg-staged, split to bf16 hi/lo in-kernel -> LDS).
// B [N][K] pre-split bf16 (Bh, Bl) staged via global_load_lds width-16.
// 128x128 tile, BK=32, 4 waves, 4x4 frags mfma_f32_16x16x32_bf16, 48 MFMA
// per k-step between one barrier pair.
// EPI 0: C[m*ldc+n] = v.   EPI 1: n<2048 -> C (x), else -> C2 (z).
// M, N multiples of 128; K multiple of 32.
// ---------------------------------------------------------------------------
template<int EPI>
__global__ __launch_bounds__(256) void gemm_mfma3(
    const float* __restrict__ A,
    const bf16_t* __restrict__ Bh, const bf16_t* __restrict__ Bl,
    float* __restrict__ C, float* __restrict__ C2,
    int N, int K, int ldc)
{
    __shared__ __align__(16) bf16_t Ash[128 * 32];
    __shared__ __align__(16) bf16_t Asl[128 * 32];
    __shared__ __align__(16) bf16_t Bsh[128 * 32];
    __shared__ __align__(16) bf16_t Bsl[128 * 32];

    const int tid  = threadIdx.x;
    const int lane = tid & 63;
    const int w    = tid >> 6;
    const int wr   = (w >> 1) * 64;
    const int wc   = (w & 1) * 64;
    const int bm   = blockIdx.x * 128;
    const int bn   = blockIdx.y * 128;
    const int l16  = lane & 15;
    const int lhi  = lane >> 4;

    f32x4 acc[4][4];
#pragma unroll
    for (int i = 0; i < 4; ++i)
#pragma unroll
        for (int j = 0; j < 4; ++j)
#pragma unroll
            for (int r = 0; r < 4; ++r) acc[i][j][r] = 0.f;

    // staging geometry: linear 16B chunks; chunk = call*256 + tid
    const int srow0 = tid >> 2;          // row for call 0
    const int sks   = (tid & 3) << 3;    // k element offset (8 bf16 = 8 fp32)
    const int wb0   = (tid & 192) * 16;  // wave-uniform LDS byte base (B path)

    for (int k0 = 0; k0 < K; k0 += 32) {
        __syncthreads();   // LDS reuse guard
#pragma unroll
        for (int call = 0; call < 2; ++call) {
            const int row = srow0 + call * 64;
            const int wb  = wb0 + call * 4096;
            GLOAD_LDS16(Bh + (size_t)(bn + row) * K + k0 + sks, (char*)Bsh + wb);
            GLOAD_LDS16(Bl + (size_t)(bn + row) * K + k0 + sks, (char*)Bsl + wb);
        }
#pragma unroll
        for (int call = 0; call < 2; ++call) {
            const int row = srow0 + call * 64;
            const float* ap = A + (size_t)(bm + row) * K + k0 + sks;
            const float4 v0 = *(const float4*)ap;
            const float4 v1 = *(const float4*)(ap + 4);
            const float fv[8] = {v0.x, v0.y, v0.z, v0.w, v1.x, v1.y, v1.z, v1.w};
            bf16x8 hv, lv;
#pragma unroll
            for (int e = 0; e < 8; ++e) {
                const bf16_t h = (bf16_t)fv[e];
                hv[e] = h;
                lv[e] = (bf16_t)(fv[e] - (float)h);
            }
            *(bf16x8*)((char*)Ash + 16 * tid + call * 4096) = hv;
            *(bf16x8*)((char*)Asl + 16 * tid + call * 4096) = lv;
        }
        __syncthreads();   // drains vmcnt (B) + lgkmcnt (A) before compute

        bf16x8 ah[4], al[4], bh[4], bl[4];
#pragma unroll
        for (int f = 0; f < 4; ++f) {
            const int ar = (wr + f * 16 + l16) * 32 + lhi * 8;
            const int br = (wc + f * 16 + l16) * 32 + lhi * 8;
            ah[f] = *(const bf16x8*)&Ash[ar];
            al[f] = *(const bf16x8*)&Asl[ar];
            bh[f] = *(const bf16x8*)&Bsh[br];
            bl[f] = *(const bf16x8*)&Bsl[br];
        }
#pragma unroll
        for (int fm = 0; fm < 4; ++fm)
#pragma unroll
            for (int fn = 0; fn < 4; ++fn) {
                acc[fm][fn] = __builtin_amdgcn_mfma_f32_16x16x32_bf16(
                    ah[fm], bh[fn], acc[fm][fn], 0, 0, 0);
                acc[fm][fn] = __builtin_amdgcn_mfma_f32_16x16x32_bf16(
                    al[fm], bh[fn], acc[fm][fn], 0, 0, 0);
                acc[fm][fn] = __builtin_amdgcn_mfma_f32_16x16x32_bf16(
                    ah[fm], bl[fn], acc[fm][fn], 0, 0, 0);
            }
    }

    // epilogue: D col = lane&15, row = (lane>>4)*4 + reg  [m89-verified]
#pragma unroll
    for (int fm = 0; fm < 4; ++fm) {
        const int row0 = bm + wr + fm * 16 + lhi * 4;
#pragma unroll
        for (int fn = 0; fn < 4; ++fn) {
            const int col = bn + wc + fn * 16 + l16;
#pragma unroll
            for (int r = 0; r < 4; ++r) {
                const float v = acc[fm][fn][r];
                const size_t m = row0 + r;
                if (EPI == 0) {
                    C[m * ldc + col] = v;
                } else {
                    if (col < 2048) C[m * 2048 + col] = v;
                    else            C2[m * 2048 + (col - 2048)] = v;
                }
            }
        }
    }
}

// ---------------------------------------------------------------------------
// Tiled fp32 NT-GEMM (small GEMMs).  EPI 0: plain.  EPI 2: bias + softplus.
// ---------------------------------------------------------------------------
template<int EPI>
__global__ __launch_bounds__(256) void gemm_nt(
    const float* __restrict__ A, const float* __restrict__ B,
    float* __restrict__ C, const float* __restrict__ bias,
    int N, int K, int lda, int ldb, int ldc)
{
    __shared__ float As[16][68];
    __shared__ float Bs[16][68];

    const int tid = threadIdx.x;
    const int tx = tid & 15;
    const int ty = tid >> 4;
    const int bm = blockIdx.x * 64;
    const int bn = blockIdx.y * 64;

    const int r  = tid >> 2;
    const int kc = (tid & 3) << 2;

    float acc[4][4];
#pragma unroll
    for (int i = 0; i < 4; ++i)
#pragma unroll
        for (int j = 0; j < 4; ++j) acc[i][j] = 0.f;

    for (int k0 = 0; k0 < K; k0 += 16) {
        float4 av = *(const float4*)(A + (size_t)(bm + r) * lda + k0 + kc);
        const int cB = bn + r;
        float4 bv = make_float4(0.f, 0.f, 0.f, 0.f);
        if (cB < N) bv = *(const float4*)(B + (size_t)cB * ldb + k0 + kc);

        As[kc + 0][r] = av.x; As[kc + 1][r] = av.y;
        As[kc + 2][r] = av.z; As[kc + 3][r] = av.w;
        Bs[kc + 0][r] = bv.x; Bs[kc + 1][r] = bv.y;
        Bs[kc + 2][r] = bv.z; Bs[kc + 3][r] = bv.w;
        __syncthreads();

#pragma unroll
        for (int kk = 0; kk < 16; ++kk) {
            float4 a4 = *(const float4*)&As[kk][ty << 2];
            float4 b4 = *(const float4*)&Bs[kk][tx << 2];
            float a[4] = {a4.x, a4.y, a4.z, a4.w};
            float b[4] = {b4.x, b4.y, b4.z, b4.w};
#pragma unroll
            for (int i = 0; i < 4; ++i)
#pragma unroll
                for (int j = 0; j < 4; ++j)
                    acc[i][j] = fmaf(a[i], b[j], acc[i][j]);
        }
        __syncthreads();
    }

#pragma unroll
    for (int i = 0; i < 4; ++i) {
        const int m = bm + (ty << 2) + i;
#pragma unroll
        for (int j = 0; j < 4; ++j) {
            const int n = bn + (tx << 2) + j;
            float v = acc[i][j];
            if (EPI == 0) {
                if (n < N) C[(size_t)m * ldc + n] = v;
            } else {
                v += bias[n];
                v = (v > 20.f) ? v : log1pf(expf(v));
                C[(size_t)m * ldc + n] = v;
            }
        }
    }
}

// ---------------------------------------------------------------------------
// Depthwise causal conv (width 4) + bias + SiLU.
// ---------------------------------------------------------------------------
__global__ __launch_bounds__(256) void conv_silu(
    const float* __restrict__ xin, const float* __restrict__ w,
    const float* __restrict__ bias, float* __restrict__ xout,
    int L, int D)
{
    const long long idx = (long long)blockIdx.x * 256 + threadIdx.x;
    const int d = (int)(idx % D);
    const long long bl = idx / D;
    const int l = (int)(bl % L);

    const float w0 = w[d * 4 + 0], w1 = w[d * 4 + 1];
    const float w2 = w[d * 4 + 2], w3 = w[d * 4 + 3];

    float acc = bias[d];
    acc = fmaf(w3, xin[idx], acc);
    if (l >= 1) acc = fmaf(w2, xin[idx - D], acc);
    if (l >= 2) acc = fmaf(w1, xin[idx - 2LL * D], acc);
    if (l >= 3) acc = fmaf(w0, xin[idx - 3LL * D], acc);

    const float s = acc / (1.f + __expf(-acc));
    xout[idx] = s;
}

// ---------------------------------------------------------------------------
// Chunked selective scan, pass 1: per-chunk local scan (h0=0) + chunk decay.
// ---------------------------------------------------------------------------
__global__ __launch_bounds__(256) void scan_chunk_local(
    const float* __restrict__ xconv, const float* __restrict__ dt,
    const float* __restrict__ xdbl,  const float* __restrict__ A_log,
    float* __restrict__ Sbuf, float* __restrict__ Pbuf)
{
    const int n      = threadIdx.x & 15;
    const int dlocal = threadIdx.x >> 4;
    const int d = blockIdx.x * 16 + dlocal;
    const int c = blockIdx.y;
    const int b = blockIdx.z;

    const float a = -__expf(A_log[d * 16 + n]);

    float S = 0.f, sumdt = 0.f;
    const long long rowBase = (long long)b * 4096 + (long long)c * CH;

#pragma unroll 4
    for (int i = 0; i < CH; ++i) {
        const long long row = rowBase + i;
        const float dtv = dt[row * 2048 + d];
        const float xv  = xconv[row * 2048 + d];
        const float Bv  = xdbl[row * 96 + 64 + n];
        const float dA  = __expf(dtv * a);
        S = fmaf(S, dA, dtv * xv * Bv);
        sumdt += dtv;
    }
    const float P = __expf(sumdt * a);
    const size_t idx = ((((size_t)b * NC + c) * 2048) + d) * 16 + n;
    Sbuf[idx] = S;
    Pbuf[idx] = P;
}

// ---------------------------------------------------------------------------
// Pass 2: sequential prefix over chunks; Sbuf becomes chunk-entering state.
// ---------------------------------------------------------------------------
__global__ __launch_bounds__(256) void scan_chunk_prefix(
    float* __restrict__ Sbuf, const float* __restrict__ Pbuf)
{
    const int tid = blockIdx.x * 256 + threadIdx.x;
    const int b  = tid >> 15;
    const int dn = tid & 32767;

    float H = 0.f;
    for (int c = 0; c < NC; ++c) {
        const size_t idx = ((size_t)b * NC + c) * 32768 + dn;
        const float S = Sbuf[idx];
        const float P = Pbuf[idx];
        Sbuf[idx] = H;
        H = fmaf(P, H, S);
    }
}

// ---------------------------------------------------------------------------
// Pass 3: seeded local scan, reduce over n, gate, store fp32 y in-place
// over xconv (same-thread read-then-write of the same slot).
// ---------------------------------------------------------------------------
__global__ __launch_bounds__(256) void scan_chunk_final(
    const float* __restrict__ xconv, const float* __restrict__ dt,
    const float* __restrict__ xdbl,  const float* __restrict__ A_log,
    const float* __restrict__ Dp,    const float* __restrict__ z,
    const float* __restrict__ Hbuf,  float* __restrict__ y)
{
    const int n      = threadIdx.x & 15;
    const int dlocal = threadIdx.x >> 4;
    const int d = blockIdx.x * 16 + dlocal;
    const int c = blockIdx.y;
    const int b = blockIdx.z;

    const float a  = -__expf(A_log[d * 16 + n]);
    const float Dv = Dp[d];

    float h = Hbuf[((((size_t)b * NC + c) * 2048) + d) * 16 + n];
    const long long rowBase = (long long)b * 4096 + (long long)c * CH;

    for (int i = 0; i < CH; ++i) {
        const long long row = rowBase + i;
        const float dtv = dt[row * 2048 + d];
        const float xv  = xconv[row * 2048 + d];
        const float Bv  = xdbl[row * 96 + 64 + n];
        const float Cv  = xdbl[row * 96 + 80 + n];
        const float dA  = __expf(dtv * a);
        h = fmaf(h, dA, dtv * xv * Bv);

        float contrib = h * Cv;
        contrib += __shfl_xor(contrib, 1);
        contrib += __shfl_xor(contrib, 2);
        contrib += __shfl_xor(contrib, 4);
        contrib += __shfl_xor(contrib, 8);

        if (n == 0) {
            const float zv = z[row * 2048 + d];
            float yv = contrib + xv * Dv;
            yv = yv * (zv / (1.f + __expf(-zv)));
            y[row * 2048 + d] = yv;
        }
    }
}

// ---------------------------------------------------------------------------
extern "C" void kernel_launch(void* const* d_in, const int* in_sizes, int n_in,
                              void* d_out, int out_size, void* d_ws, size_t ws_size,
                              hipStream_t stream)
{
    const float* hidden     = (const float*)d_in[0];
    const float* in_proj_w  = (const float*)d_in[1];
    const float* conv_w     = (const float*)d_in[2];
    const float* conv_b     = (const float*)d_in[3];
    const float* x_proj_w   = (const float*)d_in[4];
    const float* dt_proj_w  = (const float*)d_in[5];
    const float* dt_proj_b  = (const float*)d_in[6];
    const float* A_log      = (const float*)d_in[7];
    const float* Dvec       = (const float*)d_in[8];
    const float* out_proj_w = (const float*)d_in[9];
    float* out = (float*)d_out;

    const int L = 4096, dinner = 2048, dmodel = 1024;
    const int M = 2 * L;  // 8192

    // ---- workspace layout: EXACTLY R2's proven 221.25 MB footprint ----
    float* z     = (float*)d_ws;                       // M*2048 fp32
    float* xraw  = z     + (size_t)M * dinner;         // M*2048 (x, then dt)
    float* xconv = xraw  + (size_t)M * dinner;         // M*2048 (x_conv, then y)
    float* xdbl  = xconv + (size_t)M * dinner;         // M*96
    float* Sbuf  = xdbl  + (size_t)M * 96;             // 2*NC*2048*16
    float* Pbuf  = Sbuf  + (size_t)2 * NC * dinner * 16;

    // aliases (lifetime-disjoint):
    // w1 pair lives in [Sbuf..Pbuf end) -- dead before the scan writes Sbuf/Pbuf
    bf16_t* w1_h = (bf16_t*)Sbuf;                      // 2*dinner*dmodel bf16
    bf16_t* w1_l = w1_h + (size_t)2 * dinner * dmodel; //  (16.78 MB = exact fit)
    // w2 pair lives in z -- split AFTER scan_final has consumed z
    bf16_t* w2_h = (bf16_t*)z;                         // dmodel*dinner bf16
    bf16_t* w2_l = w2_h + (size_t)dmodel * dinner;

    // ---- 0. split in_proj_w into bf16 hi/lo (into Sbuf/Pbuf region) ----
    split_hl<<<(2 * dinner * dmodel / 4 + 255) / 256, 256, 0, stream>>>(
        in_proj_w, w1_h, w1_l, 2 * dinner * dmodel / 4);

    // ---- 1. in_proj (split-precision MFMA): A=hidden fp32 reg-staged ----
    gemm_mfma3<1><<<dim3(M / 128, 4096 / 128), 256, 0, stream>>>(
        hidden, w1_h, w1_l, xraw, z, 4096, dmodel, 0);

    // ---- 2. depthwise conv + bias + SiLU ----
    conv_silu<<<(M * (long long)dinner) / 256, 256, 0, stream>>>(
        xraw, conv_w, conv_b, xconv, L, dinner);

    // ---- 3. x_proj (fp32): (8192x2048)x(96x2048)^T -> xdbl ----
    gemm_nt<0><<<dim3(M / 64, 2), 256, 0, stream>>>(
        xconv, x_proj_w, xdbl, nullptr, 96, 2048, 2048, 2048, 96);

    // ---- 4. dt_proj (fp32): (8192x64)x(2048x64)^T + bias, softplus -> dt ----
    gemm_nt<2><<<dim3(M / 64, 2048 / 64), 256, 0, stream>>>(
        xdbl, dt_proj_w, xraw, dt_proj_b, 2048, 64, 96, 64, 2048);

    // ---- 5. chunked selective scan (fp32 y in-place over xconv) ----
    scan_chunk_local<<<dim3(dinner / 16, NC, 2), 256, 0, stream>>>(
        xconv, xraw, xdbl, A_log, Sbuf, Pbuf);
    scan_chunk_prefix<<<256, 256, 0, stream>>>(Sbuf, Pbuf);
    scan_chunk_final<<<dim3(dinner / 16, NC, 2), 256, 0, stream>>>(
        xconv, xraw, xdbl, A_log, Dvec, z, Sbuf, xconv);

    // ---- 5b. split out_proj_w into bf16 hi/lo (into z region, now dead) ----
    split_hl<<<(dmodel * dinner / 4 + 255) / 256, 256, 0, stream>>>(
        out_proj_w, w2_h, w2_l, dmodel * dinner / 4);

    // ---- 6. out_proj (split-precision MFMA): A=y fp32 reg-staged ----
    gemm_mfma3<0><<<dim3(M / 128, 1024 / 128), 256, 0, stream>>>(
        xconv, w2_h, w2_l, out, nullptr, 1024, dinner, 1024);
}

// Round 5
// 769.806 us; speedup vs baseline: 6.1267x; 1.4423x over previous
//
#include <hip/hip_runtime.h>
#include <cmath>

#define CH 128          // scan chunk length
#define NC 32           // 4096 / CH

typedef __bf16 bf16_t;
typedef __attribute__((ext_vector_type(8))) __bf16 bf16x8;
typedef __attribute__((ext_vector_type(4))) __bf16 bf16x4;
typedef __attribute__((ext_vector_type(4))) float f32x4;

// CK idiom: generic->AS1/AS3 via uintptr for global_load_lds (width 16).
#define GLOAD_LDS16(gp, lp)                                                     \
    __builtin_amdgcn_global_load_lds(                                           \
        (const __attribute__((address_space(1))) unsigned int*)(uintptr_t)(gp), \
        (__attribute__((address_space(3))) unsigned int*)(uintptr_t)(lp),       \
        16, 0, 0)

// ---------------------------------------------------------------------------
// fp32 -> (hi, lo) bf16 split.  4 floats per thread.
// ---------------------------------------------------------------------------
__global__ __launch_bounds__(256) void split_hl(
    const float* __restrict__ in, bf16_t* __restrict__ hi,
    bf16_t* __restrict__ lo, int n4)
{
    const int i = blockIdx.x * 256 + threadIdx.x;
    if (i >= n4) return;
    const float4 v = ((const float4*)in)[i];
    const bf16_t h0 = (bf16_t)v.x, h1 = (bf16_t)v.y,
                 h2 = (bf16_t)v.z, h3 = (bf16_t)v.w;
    bf16x4 hv = {h0, h1, h2, h3};
    bf16x4 lv = {(bf16_t)(v.x - (float)h0), (bf16_t)(v.y - (float)h1),
                 (bf16_t)(v.z - (float)h2), (bf16_t)(v.w - (float)h3)};
    ((bf16x4*)hi)[i] = hv;
    ((bf16x4*)lo)[i] = lv;
}

// ---------------------------------------------------------------------------
// Split-precision MFMA NT-GEMM:  C = A.B^T computed as Ah.Bh + Al.Bh + Ah.Bl
// A [M][K] fp32 (reg-staged, split to bf16 hi/lo in-kernel -> LDS).
// B [N][K] pre-split bf16 (Bh, Bl) staged via global_load_lds width-16.
// 128x128 tile, BK=32, 4 waves, 4x4 frags mfma_f32_16x16x32_bf16.
// EPI 0: C[m*ldc+n] = v.   EPI 1: n<2048 -> C (x), else -> C2 (z).
// ---------------------------------------------------------------------------
template<int EPI>
__global__ __launch_bounds__(256) void gemm_mfma3(
    const float* __restrict__ A,
    const bf16_t* __restrict__ Bh, const bf16_t* __restrict__ Bl,
    float* __restrict__ C, float* __restrict__ C2,
    int N, int K, int ldc)
{
    __shared__ __align__(16) bf16_t Ash[128 * 32];
    __shared__ __align__(16) bf16_t Asl[128 * 32];
    __shared__ __align__(16) bf16_t Bsh[128 * 32];
    __shared__ __align__(16) bf16_t Bsl[128 * 32];

    const int tid  = threadIdx.x;
    const int lane = tid & 63;
    const int w    = tid >> 6;
    const int wr   = (w >> 1) * 64;
    const int wc   = (w & 1) * 64;
    const int bm   = blockIdx.x * 128;
    const int bn   = blockIdx.y * 128;
    const int l16  = lane & 15;
    const int lhi  = lane >> 4;

    f32x4 acc[4][4];
#pragma unroll
    for (int i = 0; i < 4; ++i)
#pragma unroll
        for (int j = 0; j < 4; ++j)
#pragma unroll
            for (int r = 0; r < 4; ++r) acc[i][j][r] = 0.f;

    const int srow0 = tid >> 2;          // staging row, call 0
    const int sks   = (tid & 3) << 3;    // k element offset (8 elems)
    const int wb0   = (tid & 192) * 16;  // wave-uniform LDS byte base

    for (int k0 = 0; k0 < K; k0 += 32) {
        __syncthreads();   // LDS reuse guard
#pragma unroll
        for (int call = 0; call < 2; ++call) {
            const int row = srow0 + call * 64;
            const int wb  = wb0 + call * 4096;
            GLOAD_LDS16(Bh + (size_t)(bn + row) * K + k0 + sks, (char*)Bsh + wb);
            GLOAD_LDS16(Bl + (size_t)(bn + row) * K + k0 + sks, (char*)Bsl + wb);
        }
#pragma unroll
        for (int call = 0; call < 2; ++call) {
            const int row = srow0 + call * 64;
            const float* ap = A + (size_t)(bm + row) * K + k0 + sks;
            const float4 v0 = *(const float4*)ap;
            const float4 v1 = *(const float4*)(ap + 4);
            const float fv[8] = {v0.x, v0.y, v0.z, v0.w, v1.x, v1.y, v1.z, v1.w};
            bf16x8 hv, lv;
#pragma unroll
            for (int e = 0; e < 8; ++e) {
                const bf16_t h = (bf16_t)fv[e];
                hv[e] = h;
                lv[e] = (bf16_t)(fv[e] - (float)h);
            }
            *(bf16x8*)((char*)Ash + 16 * tid + call * 4096) = hv;
            *(bf16x8*)((char*)Asl + 16 * tid + call * 4096) = lv;
        }
        __syncthreads();   // drains vmcnt (B) + lgkmcnt (A) before compute

        bf16x8 ah[4], al[4], bh[4], bl[4];
#pragma unroll
        for (int f = 0; f < 4; ++f) {
            const int ar = (wr + f * 16 + l16) * 32 + lhi * 8;
            const int br = (wc + f * 16 + l16) * 32 + lhi * 8;
            ah[f] = *(const bf16x8*)&Ash[ar];
            al[f] = *(const bf16x8*)&Asl[ar];
            bh[f] = *(const bf16x8*)&Bsh[br];
            bl[f] = *(const bf16x8*)&Bsl[br];
        }
#pragma unroll
        for (int fm = 0; fm < 4; ++fm)
#pragma unroll
            for (int fn = 0; fn < 4; ++fn) {
                acc[fm][fn] = __builtin_amdgcn_mfma_f32_16x16x32_bf16(
                    ah[fm], bh[fn], acc[fm][fn], 0, 0, 0);
                acc[fm][fn] = __builtin_amdgcn_mfma_f32_16x16x32_bf16(
                    al[fm], bh[fn], acc[fm][fn], 0, 0, 0);
                acc[fm][fn] = __builtin_amdgcn_mfma_f32_16x16x32_bf16(
                    ah[fm], bl[fn], acc[fm][fn], 0, 0, 0);
            }
    }

    // epilogue: D col = lane&15, row = (lane>>4)*4 + reg  [m89-verified]
#pragma unroll
    for (int fm = 0; fm < 4; ++fm) {
        const int row0 = bm + wr + fm * 16 + lhi * 4;
#pragma unroll
        for (int fn = 0; fn < 4; ++fn) {
            const int col = bn + wc + fn * 16 + l16;
#pragma unroll
            for (int r = 0; r < 4; ++r) {
                const float v = acc[fm][fn][r];
                const size_t m = row0 + r;
                if (EPI == 0) {
                    C[m * ldc + col] = v;
                } else {
                    if (col < 2048) C[m * 2048 + col] = v;
                    else            C2[m * 2048 + (col - 2048)] = v;
                }
            }
        }
    }
}

// ---------------------------------------------------------------------------
// Tiled fp32 NT-GEMM (small GEMMs).  EPI 0: plain.  EPI 2: bias + softplus.
// ---------------------------------------------------------------------------
template<int EPI>
__global__ __launch_bounds__(256) void gemm_nt(
    const float* __restrict__ A, const float* __restrict__ B,
    float* __restrict__ C, const float* __restrict__ bias,
    int N, int K, int lda, int ldb, int ldc)
{
    __shared__ float As[16][68];
    __shared__ float Bs[16][68];

    const int tid = threadIdx.x;
    const int tx = tid & 15;
    const int ty = tid >> 4;
    const int bm = blockIdx.x * 64;
    const int bn = blockIdx.y * 64;

    const int r  = tid >> 2;
    const int kc = (tid & 3) << 2;

    float acc[4][4];
#pragma unroll
    for (int i = 0; i < 4; ++i)
#pragma unroll
        for (int j = 0; j < 4; ++j) acc[i][j] = 0.f;

    for (int k0 = 0; k0 < K; k0 += 16) {
        float4 av = *(const float4*)(A + (size_t)(bm + r) * lda + k0 + kc);
        const int cB = bn + r;
        float4 bv = make_float4(0.f, 0.f, 0.f, 0.f);
        if (cB < N) bv = *(const float4*)(B + (size_t)cB * ldb + k0 + kc);

        As[kc + 0][r] = av.x; As[kc + 1][r] = av.y;
        As[kc + 2][r] = av.z; As[kc + 3][r] = av.w;
        Bs[kc + 0][r] = bv.x; Bs[kc + 1][r] = bv.y;
        Bs[kc + 2][r] = bv.z; Bs[kc + 3][r] = bv.w;
        __syncthreads();

#pragma unroll
        for (int kk = 0; kk < 16; ++kk) {
            float4 a4 = *(const float4*)&As[kk][ty << 2];
            float4 b4 = *(const float4*)&Bs[kk][tx << 2];
            float a[4] = {a4.x, a4.y, a4.z, a4.w};
            float b[4] = {b4.x, b4.y, b4.z, b4.w};
#pragma unroll
            for (int i = 0; i < 4; ++i)
#pragma unroll
                for (int j = 0; j < 4; ++j)
                    acc[i][j] = fmaf(a[i], b[j], acc[i][j]);
        }
        __syncthreads();
    }

#pragma unroll
    for (int i = 0; i < 4; ++i) {
        const int m = bm + (ty << 2) + i;
#pragma unroll
        for (int j = 0; j < 4; ++j) {
            const int n = bn + (tx << 2) + j;
            float v = acc[i][j];
            if (EPI == 0) {
                if (n < N) C[(size_t)m * ldc + n] = v;
            } else {
                v += bias[n];
                v = (v > 20.f) ? v : log1pf(expf(v));
                C[(size_t)m * ldc + n] = v;
            }
        }
    }
}

// ---------------------------------------------------------------------------
// Depthwise causal conv (width 4) + bias + SiLU.
// ---------------------------------------------------------------------------
__global__ __launch_bounds__(256) void conv_silu(
    const float* __restrict__ xin, const float* __restrict__ w,
    const float* __restrict__ bias, float* __restrict__ xout,
    int L, int D)
{
    const long long idx = (long long)blockIdx.x * 256 + threadIdx.x;
    const int d = (int)(idx % D);
    const long long bl = idx / D;
    const int l = (int)(bl % L);

    const float w0 = w[d * 4 + 0], w1 = w[d * 4 + 1];
    const float w2 = w[d * 4 + 2], w3 = w[d * 4 + 3];

    float acc = bias[d];
    acc = fmaf(w3, xin[idx], acc);
    if (l >= 1) acc = fmaf(w2, xin[idx - D], acc);
    if (l >= 2) acc = fmaf(w1, xin[idx - 2LL * D], acc);
    if (l >= 3) acc = fmaf(w0, xin[idx - 3LL * D], acc);

    const float s = acc / (1.f + __expf(-acc));
    xout[idx] = s;
}

// ---------------------------------------------------------------------------
// Scan pass 1 (per-channel): thread owns channel d, 16 states in registers.
// B-slice of xdbl staged in LDS (broadcast reads).  Outputs S[16], P[16].
// ---------------------------------------------------------------------------
__global__ __launch_bounds__(256) void scan_local2(
    const float* __restrict__ xconv, const float* __restrict__ dt,
    const float* __restrict__ xdbl,  const float* __restrict__ A_log,
    float* __restrict__ Sbuf, float* __restrict__ Pbuf)
{
    __shared__ float Bs[CH][16];

    const int d = blockIdx.x * 256 + threadIdx.x;
    const int c = blockIdx.y;
    const int b = blockIdx.z;
    const long long rowBase = (long long)b * 4096 + (long long)c * CH;

    // stage B columns (xdbl[.., 64..79]): CH*16 floats = 512 float4
#pragma unroll
    for (int k = 0; k < 2; ++k) {
        const int e = k * 256 + threadIdx.x;       // float4 index
        const int i = e >> 2, j = (e & 3) << 2;
        *(float4*)&Bs[i][j] = *(const float4*)&xdbl[(rowBase + i) * 96 + 64 + j];
    }
    __syncthreads();

    float a[16], S[16];
#pragma unroll
    for (int n = 0; n < 16; ++n) {
        a[n] = -__expf(A_log[d * 16 + n]);
        S[n] = 0.f;
    }
    float sumdt = 0.f;

    for (int i = 0; i < CH; ++i) {
        const long long row = rowBase + i;
        const float dtv = dt[row * 2048 + d];
        const float xv  = xconv[row * 2048 + d];
        const float u   = dtv * xv;
        sumdt += dtv;
#pragma unroll
        for (int n = 0; n < 16; ++n) {
            const float dA = __expf(dtv * a[n]);
            S[n] = fmaf(S[n], dA, u * Bs[i][n]);
        }
    }

    const size_t base = ((((size_t)b * NC + c) * 2048) + d) * 16;
#pragma unroll
    for (int k = 0; k < 4; ++k) {
        *(float4*)&Sbuf[base + k * 4] =
            make_float4(S[k*4], S[k*4+1], S[k*4+2], S[k*4+3]);
        *(float4*)&Pbuf[base + k * 4] =
            make_float4(__expf(sumdt * a[k*4]),   __expf(sumdt * a[k*4+1]),
                        __expf(sumdt * a[k*4+2]), __expf(sumdt * a[k*4+3]));
    }
}

// ---------------------------------------------------------------------------
// Pass 2: sequential prefix over chunks; Sbuf becomes chunk-entering state.
// ---------------------------------------------------------------------------
__global__ __launch_bounds__(256) void scan_chunk_prefix(
    float* __restrict__ Sbuf, const float* __restrict__ Pbuf)
{
    const int tid = blockIdx.x * 256 + threadIdx.x;
    const int b  = tid >> 15;
    const int dn = tid & 32767;

    float H = 0.f;
    for (int c = 0; c < NC; ++c) {
        const size_t idx = ((size_t)b * NC + c) * 32768 + dn;
        const float S = Sbuf[idx];
        const float P = Pbuf[idx];
        Sbuf[idx] = H;
        H = fmaf(P, H, S);
    }
}

// ---------------------------------------------------------------------------
// Scan pass 3 (per-channel): seeded with H, full n-dot in registers, gate,
// fp32 y written in-place over xconv (same-thread same-slot).
// ---------------------------------------------------------------------------
__global__ __launch_bounds__(256) void scan_final2(
    const float* __restrict__ xconv, const float* __restrict__ dt,
    const float* __restrict__ xdbl,  const float* __restrict__ A_log,
    const float* __restrict__ Dp,    const float* __restrict__ z,
    const float* __restrict__ Hbuf,  float* __restrict__ y)
{
    __shared__ float BCs[CH][32];    // [l][0..15]=B, [l][16..31]=C

    const int d = blockIdx.x * 256 + threadIdx.x;
    const int c = blockIdx.y;
    const int b = blockIdx.z;
    const long long rowBase = (long long)b * 4096 + (long long)c * CH;

    // stage B+C columns: CH*32 floats = 1024 float4
#pragma unroll
    for (int k = 0; k < 4; ++k) {
        const int e = k * 256 + threadIdx.x;       // float4 index
        const int i = e >> 3, j = (e & 7) << 2;
        *(float4*)&BCs[i][j] = *(const float4*)&xdbl[(rowBase + i) * 96 + 64 + j];
    }
    __syncthreads();

    float a[16], h[16];
    const size_t hbase = ((((size_t)b * NC + c) * 2048) + d) * 16;
#pragma unroll
    for (int k = 0; k < 4; ++k) {
        const float4 hv = *(const float4*)&Hbuf[hbase + k * 4];
        h[k*4] = hv.x; h[k*4+1] = hv.y; h[k*4+2] = hv.z; h[k*4+3] = hv.w;
    }
#pragma unroll
    for (int n = 0; n < 16; ++n) a[n] = -__expf(A_log[d * 16 + n]);
    const float Dv = Dp[d];

    for (int i = 0; i < CH; ++i) {
        const long long row = rowBase + i;
        const float dtv = dt[row * 2048 + d];
        const float xv  = xconv[row * 2048 + d];
        const float u   = dtv * xv;
        float acc = 0.f;
#pragma unroll
        for (int n = 0; n < 16; ++n) {
            const float dA = __expf(dtv * a[n]);
            h[n] = fmaf(h[n], dA, u * BCs[i][n]);
            acc  = fmaf(h[n], BCs[i][16 + n], acc);
        }
        const float zv = z[row * 2048 + d];
        float yv = acc + xv * Dv;
        yv = yv * (zv / (1.f + __expf(-zv)));
        y[row * 2048 + d] = yv;
    }
}

// ---------------------------------------------------------------------------
extern "C" void kernel_launch(void* const* d_in, const int* in_sizes, int n_in,
                              void* d_out, int out_size, void* d_ws, size_t ws_size,
                              hipStream_t stream)
{
    const float* hidden     = (const float*)d_in[0];
    const float* in_proj_w  = (const float*)d_in[1];
    const float* conv_w     = (const float*)d_in[2];
    const float* conv_b     = (const float*)d_in[3];
    const float* x_proj_w   = (const float*)d_in[4];
    const float* dt_proj_w  = (const float*)d_in[5];
    const float* dt_proj_b  = (const float*)d_in[6];
    const float* A_log      = (const float*)d_in[7];
    const float* Dvec       = (const float*)d_in[8];
    const float* out_proj_w = (const float*)d_in[9];
    float* out = (float*)d_out;

    const int L = 4096, dinner = 2048, dmodel = 1024;
    const int M = 2 * L;  // 8192

    // ---- workspace layout: EXACTLY R2's proven 221.25 MB footprint ----
    float* z     = (float*)d_ws;                       // M*2048 fp32
    float* xraw  = z     + (size_t)M * dinner;         // M*2048 (x, then dt)
    float* xconv = xraw  + (size_t)M * dinner;         // M*2048 (x_conv, then y)
    float* xdbl  = xconv + (size_t)M * dinner;         // M*96
    float* Sbuf  = xdbl  + (size_t)M * 96;             // 2*NC*2048*16
    float* Pbuf  = Sbuf  + (size_t)2 * NC * dinner * 16;

    // aliases (lifetime-disjoint):
    bf16_t* w1_h = (bf16_t*)Sbuf;                      // dead before scan
    bf16_t* w1_l = w1_h + (size_t)2 * dinner * dmodel;
    bf16_t* w2_h = (bf16_t*)z;                         // split after scan uses z
    bf16_t* w2_l = w2_h + (size_t)dmodel * dinner;

    // ---- 0. split in_proj_w into bf16 hi/lo (into Sbuf/Pbuf region) ----
    split_hl<<<(2 * dinner * dmodel / 4 + 255) / 256, 256, 0, stream>>>(
        in_proj_w, w1_h, w1_l, 2 * dinner * dmodel / 4);

    // ---- 1. in_proj (split-precision MFMA) ----
    gemm_mfma3<1><<<dim3(M / 128, 4096 / 128), 256, 0, stream>>>(
        hidden, w1_h, w1_l, xraw, z, 4096, dmodel, 0);

    // ---- 2. depthwise conv + bias + SiLU ----
    conv_silu<<<(M * (long long)dinner) / 256, 256, 0, stream>>>(
        xraw, conv_w, conv_b, xconv, L, dinner);

    // ---- 3. x_proj (fp32): (8192x2048)x(96x2048)^T -> xdbl ----
    gemm_nt<0><<<dim3(M / 64, 2), 256, 0, stream>>>(
        xconv, x_proj_w, xdbl, nullptr, 96, 2048, 2048, 2048, 96);

    // ---- 4. dt_proj (fp32): (8192x64)x(2048x64)^T + bias, softplus -> dt ----
    gemm_nt<2><<<dim3(M / 64, 2048 / 64), 256, 0, stream>>>(
        xdbl, dt_proj_w, xraw, dt_proj_b, 2048, 64, 96, 64, 2048);

    // ---- 5. chunked selective scan (per-channel register-state form) ----
    scan_local2<<<dim3(dinner / 256, NC, 2), 256, 0, stream>>>(
        xconv, xraw, xdbl, A_log, Sbuf, Pbuf);
    scan_chunk_prefix<<<256, 256, 0, stream>>>(Sbuf, Pbuf);
    scan_final2<<<dim3(dinner / 256, NC, 2), 256, 0, stream>>>(
        xconv, xraw, xdbl, A_log, Dvec, z, Sbuf, xconv);

    // ---- 5b. split out_proj_w into bf16 hi/lo (into z region, now dead) ----
    split_hl<<<(dmodel * dinner / 4 + 255) / 256, 256, 0, stream>>>(
        out_proj_w, w2_h, w2_l, dmodel * dinner / 4);

    // ---- 6. out_proj (split-precision MFMA) ----
    gemm_mfma3<0><<<dim3(M / 128, 1024 / 128), 256, 0, stream>>>(
        xconv, w2_h, w2_l, out, nullptr, 1024, dinner, 1024);
}